// Round 9
// baseline (111.602 us; speedup 1.0000x reference)
//
#include <hip/hip_runtime.h>
#include <hip/hip_bf16.h>
#include <math.h>

// Problem constants: B=256, V=2048, PD=1024, MD=512, H=512
typedef __attribute__((ext_vector_type(8))) short short8;
typedef __attribute__((ext_vector_type(4))) float float4v;
typedef __attribute__((ext_vector_type(2))) float float2v;

__device__ __forceinline__ int2 cvt2bf16x4(float4v v) {
    union { __hip_bfloat162 h2; int i; } u0, u1;
    u0.h2 = __float22bfloat162_rn(make_float2(v.x, v.y));  // v_cvt_pk_bf16_f32
    u1.h2 = __float22bfloat162_rn(make_float2(v.z, v.w));
    return make_int2(u0.i, u1.i);
}

// Fused dual GEMM + exp epilogue (plain [h][x] layout, contiguous stores).
//  bx 0..3:  EA[h][b] = exp(2*(patient@W1p^T + b1))   M=256,  K=1024
//  bx 4..35: EM[h][v] = exp(2*(atc4@W1m^T))           M=2048, K=512
// NOTE (round-3 lesson): do NOT fuse cross-block reductions with
// __threadfence on this chip -- agent-scope fences flush per-XCD L2 and
// cost ~30 us. Separate dispatches keep workspace traffic L2-hot.
__global__ __launch_bounds__(256, 2) void gemm_exp(
    const float* __restrict__ patient, const float* __restrict__ atc4,
    const float* __restrict__ W1, const float* __restrict__ b1,
    float* __restrict__ EA, float* __restrict__ EM)
{
    const float* A; const float* W; const float* bias; float* T;
    int lda, K, M;
    int bx = blockIdx.x;
    if (bx < 4) {
        A = patient; lda = 1024; K = 1024; M = 256; bias = b1; T = EA; W = W1;
    } else {
        bx -= 4;
        A = atc4;    lda = 512;  K = 512;  M = 2048; bias = nullptr; T = EM; W = W1 + 1024;
    }
    const int ldw = 1536;

    __shared__ short As[64][72];
    __shared__ short Bs[64][72];
    const int t = threadIdx.x;
    const int m0 = bx * 64;
    const int n0 = blockIdx.y * 64;
    const int wave = t >> 6;
    const int lane = t & 63;
    const int wm = (wave & 1) * 32;
    const int wn = (wave >> 1) * 32;
    const int lrow = lane & 15;
    const int quad = lane >> 4;

    float4v acc[2][2];
    #pragma unroll
    for (int i = 0; i < 2; i++)
        #pragma unroll
        for (int j = 0; j < 2; j++)
            acc[i][j] = (float4v){0.f, 0.f, 0.f, 0.f};

    const int sr = t >> 2;        // staging row 0..63
    const int sc = (t & 3) * 16;  // staging col 0,16,32,48

    // preload k-tile 0 into registers
    float4v av[4], wv[4];
    {
        const float* ap = A + (size_t)(m0 + sr) * lda + sc;
        const float* wp = W + (size_t)(n0 + sr) * ldw + sc;
        #pragma unroll
        for (int ii = 0; ii < 4; ii++) {
            av[ii] = *(const float4v*)(ap + ii * 4);
            wv[ii] = *(const float4v*)(wp + ii * 4);
        }
    }

    for (int k0 = 0; k0 < K; k0 += 64) {
        #pragma unroll
        for (int ii = 0; ii < 4; ii++) {
            *(int2*)&As[sr][sc + ii * 4] = cvt2bf16x4(av[ii]);
            *(int2*)&Bs[sr][sc + ii * 4] = cvt2bf16x4(wv[ii]);
        }
        __syncthreads();
        if (k0 + 64 < K) {   // prefetch next k-tile; latency hides under MFMA
            const float* ap = A + (size_t)(m0 + sr) * lda + (k0 + 64 + sc);
            const float* wp = W + (size_t)(n0 + sr) * ldw + (k0 + 64 + sc);
            #pragma unroll
            for (int ii = 0; ii < 4; ii++) {
                av[ii] = *(const float4v*)(ap + ii * 4);
                wv[ii] = *(const float4v*)(wp + ii * 4);
            }
        }
        #pragma unroll
        for (int kk = 0; kk < 64; kk += 32) {
            short8 af[2], bfr[2];
            #pragma unroll
            for (int i = 0; i < 2; i++)
                af[i] = *(const short8*)&As[wm + i * 16 + lrow][kk + quad * 8];
            #pragma unroll
            for (int j = 0; j < 2; j++)
                bfr[j] = *(const short8*)&Bs[wn + j * 16 + lrow][kk + quad * 8];
            #pragma unroll
            for (int i = 0; i < 2; i++)
                #pragma unroll
                for (int j = 0; j < 2; j++)
                    acc[i][j] = __builtin_amdgcn_mfma_f32_16x16x32_bf16(
                        af[i], bfr[j], acc[i][j], 0, 0, 0);
        }
        __syncthreads();
    }

    // D layout (verified m89/m91): col(n)=lane&15, row(m)=quad*4+reg
    #pragma unroll
    for (int i = 0; i < 2; i++) {
        #pragma unroll
        for (int j = 0; j < 2; j++) {
            const int n  = n0 + wn + j * 16 + lrow;
            const int mb = m0 + wm + i * 16 + quad * 4;
            const float bn = bias ? bias[n] : 0.0f;
            float4v ev;
            #pragma unroll
            for (int r = 0; r < 4; r++)
                ev[r] = __expf(2.0f * (acc[i][j][r] + bn));
            *(float4v*)&T[(size_t)n * M + mb] = ev;
        }
    }
}

__device__ __forceinline__ float4v splat4(float x) {
    return (float4v){x, x, x, x};
}

// partial[z][b][v] = sum_{h in 64-chunk z} [ w2[h] + c_h / d_h ],
//   c = -2*w2, d = 1 + Ea[h][b]*Em[h][v]    (w2*tanh(x) = w2 - 2*w2/(1+e^{2x}))
// Round 9: inner math rewritten on float4v (full v-quad vectors, no L/H
// float2 split). R4's direct measurement (41.8 us, VALUBusy 34%, 1 wave/
// SIMD) back-solves to ~17K VALU inst/thread vs ~3.6K if packed-fp32 were
// emitted -- the float2v form was scalarized. Same algebra, same LDS
// pattern, same 4v x 4b blocking and (32,4,8) grid as R8; only the value
// representation changes, so clang can emit v_pk_fma_f32 pairs.
__global__ __launch_bounds__(256, 4) void pair_kernel(
    const float* __restrict__ EA, const float* __restrict__ EM,
    const float* __restrict__ w2, float* __restrict__ partial)
{
    __shared__ float sEA[64][68];    // [h][b], 64 cols used
    __shared__ float sEM[64][68];    // [h][v], 64 cols used
    __shared__ float4v sC4[16];      // -2*w2 quads for the 64-h chunk
    const int t  = threadIdx.x;
    const int v0 = blockIdx.x * 64;
    const int b0 = blockIdx.y * 64;
    const int h0 = blockIdx.z * 64;
    const int tx = t & 15;   // v = v0 + tx*4 + j
    const int ty = t >> 4;   // b = b0 + ty*4 + i

    if (t < 16) {
        float4v wvq = *(const float4v*)(w2 + h0 + 4 * t);
        sC4[t] = -2.0f * wvq;
    }

    float4v acc[4];                  // [b] x v-quad
    #pragma unroll
    for (int i = 0; i < 4; i++)
        acc[i] = (float4v){0.f, 0.f, 0.f, 0.f};

    // ---- stage the block's 64-h chunk (once): 4 threads/row, 4 float4 each
    {
        const int rS = t >> 2;            // row 0..63
        const int c0i = (t & 3) * 16;     // col 0,16,32,48
        const float* pa = EA + (size_t)(h0 + rS) * 256 + b0 + c0i;
        const float* pm = EM + (size_t)(h0 + rS) * 2048 + v0 + c0i;
        #pragma unroll
        for (int i = 0; i < 4; i++) {
            float4v va = *(const float4v*)(pa + 4 * i);
            float4v vm = *(const float4v*)(pm + 4 * i);
            *(float4v*)&sEA[rS][c0i + 4 * i] = va;
            *(float4v*)&sEM[rS][c0i + 4 * i] = vm;
        }
    }
    __syncthreads();

    const float4v one4 = {1.f, 1.f, 1.f, 1.f};

    #pragma unroll 1
    for (int q = 0; q < 16; q++) {       // 4 h per iteration
        const int hq = 4 * q;
        const float4v m0 = *(const float4v*)&sEM[hq    ][tx * 4];
        const float4v m1 = *(const float4v*)&sEM[hq + 1][tx * 4];
        const float4v m2 = *(const float4v*)&sEM[hq + 2][tx * 4];
        const float4v m3 = *(const float4v*)&sEM[hq + 3][tx * 4];
        const float4v ea0 = *(const float4v*)&sEA[hq    ][ty * 4];
        const float4v ea1 = *(const float4v*)&sEA[hq + 1][ty * 4];
        const float4v ea2 = *(const float4v*)&sEA[hq + 2][ty * 4];
        const float4v ea3 = *(const float4v*)&sEA[hq + 3][ty * 4];
        const float4v c = sC4[q];
        const float4v c0 = splat4(c.x);
        const float4v c1 = splat4(c.y);
        const float4v c2 = splat4(c.z);
        const float4v c3 = splat4(c.w);
        #pragma unroll
        for (int i = 0; i < 4; i++) {    // b within the thread's 4
            const float4v d0 = __builtin_elementwise_fma(m0, splat4(ea0[i]), one4);
            const float4v d1 = __builtin_elementwise_fma(m1, splat4(ea1[i]), one4);
            const float4v d2 = __builtin_elementwise_fma(m2, splat4(ea2[i]), one4);
            const float4v d3 = __builtin_elementwise_fma(m3, splat4(ea3[i]), one4);
            const float4v e01 = d0 * d1;
            const float4v e23 = d2 * d3;
            const float4v n01 = __builtin_elementwise_fma(d1, c0, d0 * c1);
            const float4v n23 = __builtin_elementwise_fma(d3, c2, d2 * c3);
            const float4v num = __builtin_elementwise_fma(n01, e23, n23 * e01);
            const float4v den = e01 * e23;
            const float4v r = { __builtin_amdgcn_rcpf(den.x),
                                __builtin_amdgcn_rcpf(den.y),
                                __builtin_amdgcn_rcpf(den.z),
                                __builtin_amdgcn_rcpf(den.w) };
            acc[i] = __builtin_elementwise_fma(num, r, acc[i]);
        }
    }

    // chunk's sum(w2) from sC4 (sC4 = -2*w2)
    float4v w2q = sC4[0];
    #pragma unroll
    for (int k = 1; k < 16; k++) w2q += sC4[k];
    const float w2s = -0.5f * (w2q.x + w2q.y + w2q.z + w2q.w);
    const float4v w2s4 = splat4(w2s);

    const size_t pb = (size_t)blockIdx.z * (256 * 2048);
    #pragma unroll
    for (int i = 0; i < 4; i++) {
        const size_t row = pb + (size_t)(b0 + ty * 4 + i) * 2048 + v0 + tx * 4;
        float4v o = acc[i] + w2s4;
        *(float4v*)&partial[row] = o;
    }
}

__global__ __launch_bounds__(256) void reduce_kernel(
    const float* __restrict__ partial, const float* __restrict__ b2,
    float* __restrict__ out)
{
    const int i = (blockIdx.x * 256 + threadIdx.x) * 4;
    const float bb = b2[0];
    float4v s = *(const float4v*)&partial[i];
    #pragma unroll
    for (int z = 1; z < 8; z++)
        s += *(const float4v*)&partial[(size_t)z * 524288 + i];
    float4v o = s + bb;
    *(float4v*)&out[i] = o;
}

extern "C" void kernel_launch(void* const* d_in, const int* in_sizes, int n_in,
                              void* d_out, int out_size, void* d_ws, size_t ws_size,
                              hipStream_t stream)
{
    const float* patient = (const float*)d_in[0]; // 256x1024
    const float* atc4    = (const float*)d_in[1]; // 2048x512
    const float* W1      = (const float*)d_in[2]; // 512x1536
    const float* b1      = (const float*)d_in[3]; // 512
    const float* w2      = (const float*)d_in[4]; // 512
    const float* b2      = (const float*)d_in[5]; // 1
    float* out = (float*)d_out;
    float* ws  = (float*)d_ws;

    // ws layout (floats): EA[512][256], EM[512][2048],
    //                     partial[8][256][2048] => ~21.5 MB
    float* EA      = ws;
    float* EM      = ws + 131072;
    float* partial = ws + 1179648;

    // Both GEMMs in one dispatch (compacted grid, EA tiles first); exp(2x) epilogue
    gemm_exp<<<dim3(36, 8, 1), 256, 0, stream>>>(patient, atc4, W1, b1, EA, EM);
    // score partials: float4v inner math, 4v x 4b threads, 64h blocks, 4 blk/CU
    pair_kernel<<<dim3(32, 4, 8), 256, 0, stream>>>(EA, EM, w2, partial);
    // sum 8 h-chunks + b2
    reduce_kernel<<<512, 256, 0, stream>>>(partial, b2, out);
}